// Round 7
// baseline (266.055 us; speedup 1.0000x reference)
//
#include <hip/hip_runtime.h>

typedef _Float16 f16;
typedef _Float16 f16x2 __attribute__((ext_vector_type(2)));
typedef _Float16 f16x4 __attribute__((ext_vector_type(4)));
typedef _Float16 f16x8 __attribute__((ext_vector_type(8)));
typedef float    f32x4 __attribute__((ext_vector_type(4)));

// Geometry:
//   x:   (4,128,64,64) f32     p5: (128,21,64,64) f32
//   p6:  (128,21,128)  f32     out:(4,128,64,64)  f32
// Workspace (80.1 MB):
//   xkTg [4g][3kc][4n][82row][64w][32c] f16 = x/8, g-major c-inner   (outp A)
//   p5Tg [4g][21rk][64h][64w][32c] f16     = p5, g-major c-inner     (outp A)
//   t6T  [4n][128d][2688]  f16             = p6 * t3, d-major        (outp B)
//   xk   [3kc][4n][128c][82row][64w] f16   = x/8, w-inner            (gram operands)
//   t3p  [16ks][4n][11rki][128c][128d] f16 = split-K Gram partials (rk 0..10 only;
//        rk 11..20 = transpose of slice 20-rk, exact by lag symmetry)
//   t8p  [8s][4n][64h][64w][128d] f16      = split-K out partials (s = js*4+g)
//        t8p ALIASES xk+t3p region (both dead before outp runs)
#define XROWS 82
#define XSTR  (XROWS * 64)                                  // 5248
static const size_t XKT_OFF = 0;                            // 16,121,856 B
static const size_t P5T_OFF = 16121856;                     // 22,020,096 B
static const size_t T6T_OFF = P5T_OFF + 22020096;           // 2,752,512 B
static const size_t XK_OFF  = T6T_OFF + 2752512;            // 16,121,856 B
static const size_t T3P_OFF = XK_OFF + 16121856;            // 23,068,672 B -> end 80,084,992
static const size_t T8P_OFF = XK_OFF;                       // 33,554,432 B -> end 74,448,896 (fits)

// ---------------------------------------------------------------- prepX: x -> xk AND xkTg
// grid 984 = (kc*4+n)*82 + row; block 256
__global__ __launch_bounds__(256) void prepX_kernel(const float* __restrict__ x,
                                                    f16* __restrict__ xkT,
                                                    f16* __restrict__ xk) {
  __shared__ float T[128][65];
  unsigned b   = blockIdx.x;
  unsigned row = b % 82u;
  unsigned t2_ = b / 82u;
  unsigned n   = t2_ & 3u;
  unsigned kc  = t2_ >> 2;
  int hsrc = (int)row - 9;
  unsigned tid = threadIdx.x;
  unsigned w = tid & 63u, g = tid >> 6;
  f16* oT = xkT + (((size_t)(g * 3u + kc) * 4u + n) * 82u + row) * 2048u;
  f16* oX = xk + ((size_t)(kc * 4u + n) * 128u + (tid >> 1)) * XSTR + row * 64u + (tid & 1u) * 32u;

  if (hsrc >= 0 && hsrc < 64) {
    unsigned c = tid >> 1, half = (tid & 1u) * 32u;
    const float* src = x + ((size_t)(n * 128u + c) * 64u + (unsigned)hsrc) * 64u + half;
#pragma unroll
    for (int i = 0; i < 8; i++) {
      f32x4 v = *(const f32x4*)(src + i * 4);
      *(f32x4*)&T[c][half + (unsigned)i * 4u] = v;
    }
    __syncthreads();
    // xkTg: c-inner
    int wsrc = (int)w + 2 * (int)kc - 2;
    bool ok = (wsrc >= 0 && wsrc < 64);
#pragma unroll
    for (unsigned s = 0; s < 4u; s++) {
      f16x8 o;
#pragma unroll
      for (int i = 0; i < 8; i++)
        o[i] = ok ? (f16)(T[g * 32u + s * 8u + (unsigned)i][wsrc] * 0.125f) : (f16)0.f;
      *(f16x8*)(oT + w * 32u + s * 8u) = o;
    }
    // xk: w-inner
#pragma unroll
    for (unsigned s = 0; s < 4u; s++) {
      f16x8 o;
#pragma unroll
      for (int i = 0; i < 8; i++) {
        int ws = (int)(half + s * 8u + (unsigned)i) + 2 * (int)kc - 2;
        o[i] = (ws >= 0 && ws < 64) ? (f16)(T[c][ws] * 0.125f) : (f16)0.f;
      }
      *(f16x8*)(oX + s * 8u) = o;
    }
  } else {
    f16x8 z = {};
#pragma unroll
    for (unsigned s = 0; s < 4u; s++) *(f16x8*)(oT + w * 32u + s * 8u) = z;
#pragma unroll
    for (unsigned s = 0; s < 4u; s++) *(f16x8*)(oX + s * 8u) = z;
  }
}

// ---------------------------------------------------------------- prepP (p5Tg, g-major c32-inner)
__global__ __launch_bounds__(256) void prepP_kernel(const float* __restrict__ p5,
                                                    f16* __restrict__ p5T) {
  __shared__ float T[128][65];
  unsigned b  = blockIdx.x;
  unsigned h  = b & 63u;
  unsigned rk = b >> 6;
  unsigned tid = threadIdx.x;
  unsigned c = tid >> 1, half = (tid & 1u) * 32u;
  const float* src = p5 + ((size_t)c * 21u + rk) * 4096u + h * 64u + half;
#pragma unroll
  for (int i = 0; i < 8; i++) {
    f32x4 v = *(const f32x4*)(src + i * 4);
    *(f32x4*)&T[c][half + (unsigned)i * 4u] = v;
  }
  __syncthreads();
  unsigned w = tid & 63u, g = tid >> 6;
  f16* oplane = p5T + ((size_t)(g * 21u + rk) * 64u + h) * 2048u;
#pragma unroll
  for (unsigned s = 0; s < 4u; s++) {
    f16x8 o;
#pragma unroll
    for (int i = 0; i < 8; i++)
      o[i] = (f16)T[g * 32u + s * 8u + (unsigned)i][w];
    *(f16x8*)(oplane + w * 32u + s * 8u) = o;
  }
}

// ---------------------------------------------------------------- gram v5: rk 0..10 only, ks x16
// grid 1408 = n(4)*rki(11)*cseg(2)*ks(16); block 256 (4 waves 2x2), tile 64c x 128d, K=256
__global__ __launch_bounds__(256, 4) void gram_kernel(const f16* __restrict__ xk,
                                                      f16* __restrict__ t3p) {
  unsigned b    = blockIdx.x;
  unsigned ks   = b & 15u;
  unsigned cseg = (b >> 4) & 1u;
  unsigned rki  = (b >> 5) % 11u;
  unsigned n    = b / (32u * 11u);
  unsigned r    = rki / 3u;
  unsigned kc   = rki - r * 3u;

  unsigned tid  = threadIdx.x;
  unsigned wv   = tid >> 6;
  unsigned lane = tid & 63u;
  unsigned wy   = wv >> 1;
  unsigned wx   = wv & 1u;
  unsigned quad = lane >> 4;
  unsigned l16  = lane & 15u;

  f32x4 acc[2][4] = {};

  const f16* Abase = xk + (size_t)(kc * 4u + n) * 128u * XSTR;
  const f16* Bbase = xk + (size_t)(4u + n) * 128u * XSTR;
  unsigned cA = cseg * 64u + wy * 32u + l16;
  unsigned dB = wx * 64u + l16;
  unsigned h0 = ks * 4u;
  unsigned abase = (h0 + 3u * r) * 64u + quad * 8u;
  unsigned bbase = (h0 + 9u) * 64u + quad * 8u;
  const f16* Ap[2];
  const f16* Bp[4];
#pragma unroll
  for (int ms = 0; ms < 2; ms++) Ap[ms] = Abase + (size_t)(cA + ms * 16u) * XSTR + abase;
#pragma unroll
  for (int ns = 0; ns < 4; ns++) Bp[ns] = Bbase + (size_t)(dB + ns * 16u) * XSTR + bbase;

  // 8 K-steps of 32; 2-slot register pipeline
  f16x8 fa[2][2], fb[2][4];
#pragma unroll
  for (int ms = 0; ms < 2; ms++) fa[0][ms] = *(const f16x8*)(Ap[ms]);
#pragma unroll
  for (int ns = 0; ns < 4; ns++) fb[0][ns] = *(const f16x8*)(Bp[ns]);

#pragma unroll
  for (unsigned s = 0; s < 8u; s++) {
    unsigned cur = s & 1u, nxt = cur ^ 1u;
    if (s < 7u) {
      unsigned off = 32u * (s + 1u);
#pragma unroll
      for (int ms = 0; ms < 2; ms++) fa[nxt][ms] = *(const f16x8*)(Ap[ms] + off);
#pragma unroll
      for (int ns = 0; ns < 4; ns++) fb[nxt][ns] = *(const f16x8*)(Bp[ns] + off);
    }
#pragma unroll
    for (int ms = 0; ms < 2; ms++)
#pragma unroll
      for (int ns = 0; ns < 4; ns++)
        acc[ms][ns] = __builtin_amdgcn_mfma_f32_16x16x32_f16(fa[cur][ms], fb[cur][ns], acc[ms][ns], 0, 0, 0);
  }

  f16* tp = t3p + ((size_t)(ks * 4u + n) * 11u + rki) * 16384u;
#pragma unroll
  for (int ms = 0; ms < 2; ms++) {
#pragma unroll
    for (int ns = 0; ns < 4; ns++) {
      unsigned c0 = cseg * 64u + wy * 32u + (unsigned)ms * 16u + quad * 4u;
      unsigned d  = wx * 64u + (unsigned)ns * 16u + l16;
#pragma unroll
      for (int reg = 0; reg < 4; reg++)
        tp[(size_t)(c0 + (unsigned)reg) * 128u + d] = (f16)acc[ms][ns][reg];
    }
  }
}

// ---------------------------------------------------------------- ep: t6T = p6 * t3 (w/ mirror)
// grid 1344; rk<=10: direct slice; rk>=11: t3[c,rk,d] = stored[20-rk][d][c]
__global__ __launch_bounds__(256) void ep_kernel(const f16* __restrict__ t3p,
                                                 const float* __restrict__ p6,
                                                 f16* __restrict__ t6T) {
  unsigned idx = blockIdx.x * 256u + threadIdx.x;   // < 344064
  unsigned t   = idx >> 12;                          // n*21+rk
  unsigned rk  = t % 21u;
  unsigned n   = t / 21u;

  if (rk <= 10u) {
    unsigned d4 = idx & 31u;
    unsigned c  = (idx >> 5) & 127u;
    unsigned d0 = d4 * 4u;
    float s0 = 0.f, s1 = 0.f, s2 = 0.f, s3 = 0.f;
#pragma unroll
    for (unsigned ks = 0; ks < 16u; ks++) {
      f16x4 v = *(const f16x4*)(t3p + (((size_t)(ks * 4u + n) * 11u + rk) * 16384u + c * 128u + d0));
      s0 += (float)v[0]; s1 += (float)v[1]; s2 += (float)v[2]; s3 += (float)v[3];
    }
    const float* pp = p6 + ((size_t)c * 21u + rk) * 128u + d0;
    f16* ob = t6T + (size_t)(n * 128u + d0) * 2688u + rk * 128u + c;
    ob[0]        = (f16)(s0 * pp[0]);
    ob[2688]     = (f16)(s1 * pp[1]);
    ob[2 * 2688] = (f16)(s2 * pp[2]);
    ob[3 * 2688] = (f16)(s3 * pp[3]);
  } else {
    unsigned mrk = 20u - rk;
    unsigned c4 = idx & 31u;
    unsigned d  = (idx >> 5) & 127u;
    unsigned c0 = c4 * 4u;
    float s0 = 0.f, s1 = 0.f, s2 = 0.f, s3 = 0.f;
#pragma unroll
    for (unsigned ks = 0; ks < 16u; ks++) {
      f16x4 v = *(const f16x4*)(t3p + (((size_t)(ks * 4u + n) * 11u + mrk) * 16384u + d * 128u + c0));
      s0 += (float)v[0]; s1 += (float)v[1]; s2 += (float)v[2]; s3 += (float)v[3];
    }
    f16x4 o;
    o[0] = (f16)(s0 * p6[((size_t)(c0 + 0u) * 21u + rk) * 128u + d]);
    o[1] = (f16)(s1 * p6[((size_t)(c0 + 1u) * 21u + rk) * 128u + d]);
    o[2] = (f16)(s2 * p6[((size_t)(c0 + 2u) * 21u + rk) * 128u + d]);
    o[3] = (f16)(s3 * p6[((size_t)(c0 + 3u) * 21u + rk) * 128u + d]);
    *(f16x4*)(t6T + (size_t)(n * 128u + d) * 2688u + rk * 128u + c0) = o;
  }
}

// ---------------------------------------------------------------- outp v3 (no LDS, max TLP)
// grid 4096 = n(4)*h(64)*js(2)*g(4)*ws2(2); block 256 (4 waves), tile 32w x 128d.
// Wave: 16w x 64d (1 ms x 4 ns). Partials d-inner: t8p[js*4+g][n][h][w][d].
template <int J0, int J1>
__device__ __forceinline__ void outp_loop(const f16* __restrict__ xkT,
                                          const f16* __restrict__ p5T,
                                          const f16* __restrict__ bfb,
                                          unsigned g, unsigned n, unsigned h,
                                          unsigned awoff, f32x4 acc[4]) {
#pragma unroll
  for (int j = J0; j < J1; j++) {
    unsigned r  = (unsigned)j / 3u;
    unsigned kc = (unsigned)j % 3u;
    const f16* xp = xkT + (((size_t)(g * 3u + kc) * 4u + n) * 82u + h + 3u * r) * 2048u + awoff;
    const f16* pp = p5T + ((size_t)(g * 21u + (unsigned)j) * 64u + h) * 2048u + awoff;
    f16x8 xa = *(const f16x8*)xp;
    f16x8 pa = *(const f16x8*)pp;
    f16x8 bf[4];
#pragma unroll
    for (int ns = 0; ns < 4; ns++)
      bf[ns] = *(const f16x8*)(bfb + (size_t)ns * 16u * 2688u + (unsigned)j * 128u);
    f16x8 av = xa * pa + xa;   // packed f16 fma
#pragma unroll
    for (int ns = 0; ns < 4; ns++)
      acc[ns] = __builtin_amdgcn_mfma_f32_16x16x32_f16(av, bf[ns], acc[ns], 0, 0, 0);
  }
}

__global__ __launch_bounds__(256, 8) void outp_kernel(const f16* __restrict__ xkT,
                                                      const f16* __restrict__ p5T,
                                                      const f16* __restrict__ t6T,
                                                      f16* __restrict__ t8p) {
  unsigned b   = blockIdx.x;
  unsigned ws2 = b & 1u;
  unsigned g   = (b >> 1) & 3u;
  unsigned js  = (b >> 3) & 1u;
  unsigned h   = (b >> 4) & 63u;
  unsigned n   = b >> 10;

  unsigned tid  = threadIdx.x;
  unsigned wv   = tid >> 6;
  unsigned lane = tid & 63u;
  unsigned wyy  = wv >> 1;     // 16-w half within 32-w tile
  unsigned wxx  = wv & 1u;     // d 64-half
  unsigned quad = lane >> 4;
  unsigned l16  = lane & 15u;

  unsigned wloc  = ws2 * 32u + wyy * 16u + l16;                 // global w of A row
  unsigned awoff = wloc * 32u + quad * 8u;
  const f16* bfb = t6T + (size_t)(n * 128u + wxx * 64u + l16) * 2688u + g * 32u + quad * 8u;

  f32x4 acc[4] = {};
  if (js == 0u) outp_loop<0, 11>(xkT, p5T, bfb, g, n, h, awoff, acc);
  else          outp_loop<11, 21>(xkT, p5T, bfb, g, n, h, awoff, acc);

  // d-inner f16 partial stores
  f16* base = t8p + (((size_t)((js * 4u + g) * 4u + n) * 64u + h)) * 8192u;
  unsigned w0 = ws2 * 32u + wyy * 16u + quad * 4u;
#pragma unroll
  for (int ns = 0; ns < 4; ns++) {
    unsigned d = wxx * 64u + (unsigned)ns * 16u + l16;
#pragma unroll
    for (int reg = 0; reg < 4; reg++)
      base[(size_t)(w0 + (unsigned)reg) * 128u + d] = (f16)acc[ns][reg];
  }
}

// ---------------------------------------------------------------- red: out = FS * sum_s(t8p), w-transpose
// grid 512 = n(4)*h(64)*dh(2); block 256; tile 64w x 64d
#define RTW 66
__global__ __launch_bounds__(256) void red_kernel(const f16* __restrict__ t8p,
                                                  float* __restrict__ out) {
  __shared__ float Rt[64 * RTW];   // [dl][w]
  unsigned b  = blockIdx.x;
  unsigned dh = b & 1u;
  unsigned h  = (b >> 1) & 63u;
  unsigned n  = b >> 7;
  unsigned tid = threadIdx.x;
  const float FS = 0.15430334996209192f;  // 8 / sqrt(2688)

#pragma unroll
  for (unsigned i = 0; i < 2u; i++) {
    unsigned e = tid + 256u * i;       // 0..511
    unsigned w = e >> 3, seg = e & 7u; // dl0 = seg*8
    float s[8] = {};
#pragma unroll
    for (unsigned sl = 0; sl < 8u; sl++) {
      f16x8 v = *(const f16x8*)(t8p + (((size_t)(sl * 4u + n) * 64u + h)) * 8192u
                                + (size_t)w * 128u + dh * 64u + seg * 8u);
#pragma unroll
      for (int k = 0; k < 8; k++) s[k] += (float)v[k];
    }
#pragma unroll
    for (int k = 0; k < 8; k++)
      Rt[(seg * 8u + (unsigned)k) * RTW + w] = s[k] * FS;
  }
  __syncthreads();
  unsigned dl = tid >> 2, qw = (tid & 3u) * 16u;
  float* op = out + ((size_t)(n * 128u + dh * 64u + dl) * 64u + h) * 64u + qw;
#pragma unroll
  for (unsigned k = 0; k < 4u; k++) {
    f32x4 o;
#pragma unroll
    for (int i = 0; i < 4; i++) o[i] = Rt[dl * RTW + qw + k * 4u + (unsigned)i];
    *(f32x4*)(op + k * 4u) = o;
  }
}

// ---------------------------------------------------------------- launch
extern "C" void kernel_launch(void* const* d_in, const int* in_sizes, int n_in,
                              void* d_out, int out_size, void* d_ws, size_t ws_size,
                              hipStream_t stream) {
  const float* x  = (const float*)d_in[0];
  const float* p5 = (const float*)d_in[1];
  const float* p6 = (const float*)d_in[2];
  float* out = (float*)d_out;
  f16* xkT = (f16*)((char*)d_ws + XKT_OFF);
  f16* p5T = (f16*)((char*)d_ws + P5T_OFF);
  f16* t6T = (f16*)((char*)d_ws + T6T_OFF);
  f16* xk  = (f16*)((char*)d_ws + XK_OFF);
  f16* t3p = (f16*)((char*)d_ws + T3P_OFF);
  f16* t8p = (f16*)((char*)d_ws + T8P_OFF);   // aliases xk+t3p (dead by then)

  hipLaunchKernelGGL(prepX_kernel, dim3(984),  dim3(256), 0, stream, x, xkT, xk);
  hipLaunchKernelGGL(prepP_kernel, dim3(1344), dim3(256), 0, stream, p5, p5T);
  hipLaunchKernelGGL(gram_kernel,  dim3(1408), dim3(256), 0, stream, xk, t3p);
  hipLaunchKernelGGL(ep_kernel,    dim3(1344), dim3(256), 0, stream, t3p, p6, t6T);
  hipLaunchKernelGGL(outp_kernel,  dim3(4096), dim3(256), 0, stream, xkT, p5T, t6T, t8p);
  hipLaunchKernelGGL(red_kernel,   dim3(512),  dim3(256), 0, stream, t8p, out);
}

// Round 8
// 166.120 us; speedup vs baseline: 1.6016x; 1.6016x over previous
//
#include <hip/hip_runtime.h>

typedef _Float16 f16;
typedef _Float16 f16x2 __attribute__((ext_vector_type(2)));
typedef _Float16 f16x4 __attribute__((ext_vector_type(4)));
typedef _Float16 f16x8 __attribute__((ext_vector_type(8)));
typedef float    f32x4 __attribute__((ext_vector_type(4)));

// Geometry:
//   x:   (4,128,64,64) f32     p5: (128,21,64,64) f32
//   p6:  (128,21,128)  f32     out:(4,128,64,64)  f32
// Workspace:
//   xk  [3][4][128][82][64] f16 = x*(1/8), pre-shifted per kc, zero-padded rows
//   t6T [4][128][2688]      f16 = p6 * t3, d-major
//   t3p [8][4][11][128][128] f16 = split-K Gram partials, rki 0..10 ONLY
//        (t3[c,rk,d] = t3[d,20-rk,c] exactly — lag symmetry; ep mirrors rk>=11)
//   t8p [4][4][64][128][64]  f16 = split-K out partials (g,n,h,d,w), ALIASES t3p
#define XROWS 82
#define XSTR  (XROWS * 64)
#define XK_ELEMS (3u * 4u * 128u * (unsigned)XSTR)
static const size_t T6T_OFF   = (size_t)XK_ELEMS * 2;                 // 16.12 MB
static const size_t T6T_BYTES = (size_t)4 * 128 * 2688 * 2;           // 2.75 MB
static const size_t T3P_OFF   = T6T_OFF + T6T_BYTES;
static const size_t T8P_OFF   = T3P_OFF;   // t3p dead before outp writes t8p

__device__ __forceinline__ void gl16(const f16* g, f16* l) {
  __builtin_amdgcn_global_load_lds((const __attribute__((address_space(1))) void*)g,
                                   (__attribute__((address_space(3))) void*)l, 16, 0, 0);
}

// ---------------------------------------------------------------- prep (xk, w-inner)
__global__ __launch_bounds__(256) void prep_kernel(const float* __restrict__ x,
                                                   f16* __restrict__ xk) {
  unsigned p = blockIdx.x * 256u + threadIdx.x;
  unsigned total = 3u * 4u * 128u * 82u * 32u;
  if (p >= total) return;
  unsigned wp   = p & 31u;
  unsigned row  = (p >> 5) % 82u;
  unsigned rest = p / (32u * 82u);
  unsigned c    = rest & 127u;
  unsigned rest2 = rest >> 7;
  unsigned n    = rest2 & 3u;
  unsigned kc   = rest2 >> 2;
  int hsrc = (int)row - 9;
  int wsrc = (int)(wp * 2u) + 2 * (int)kc - 2;
  f16x2 v; v.x = (f16)0.f; v.y = (f16)0.f;
  if (hsrc >= 0 && hsrc < 64 && wsrc >= 0 && wsrc < 64) {
    const float2* src = (const float2*)(x + (((size_t)(n * 128u + c) * 64u + (unsigned)hsrc) * 64u + (unsigned)wsrc));
    float2 xv = *src;
    v.x = (f16)(xv.x * 0.125f);
    v.y = (f16)(xv.y * 0.125f);
  }
  ((f16x2*)xk)[p] = v;
}

// ---------------------------------------------------------------- gram (LDS-staged, rki 0..10, split-K)
// grid 704 = n(4)*rki(11)*cseg(2)*ks(8); block 256 (4 waves 2x2), tile 64c x 128d, K-slice 512, 8 steps.
__global__ __launch_bounds__(256, 3) void gram_kernel(const f16* __restrict__ xk,
                                                      f16* __restrict__ t3p) {
  __shared__ f16 gl[2 * 12288];

  unsigned b    = blockIdx.x;
  unsigned ks   = b & 7u;
  unsigned cseg = (b >> 3) & 1u;
  unsigned rki  = (b >> 4) % 11u;
  unsigned n    = b / 176u;
  unsigned r    = rki / 3u;
  unsigned kc   = rki - r * 3u;

  unsigned tid  = threadIdx.x;
  unsigned wv   = tid >> 6;
  unsigned lane = tid & 63u;
  unsigned wy   = wv >> 1;
  unsigned wx   = wv & 1u;
  unsigned quad = lane >> 4;
  unsigned l16  = lane & 15u;
  unsigned rsl  = lane >> 3;
  unsigned seg  = (lane & 7u) ^ (rsl & 7u);

  unsigned h0 = ks * 8u;
  const f16* Ab = xk + (size_t)(kc * 4u + n) * 128u * XSTR + (size_t)(cseg * 64u) * XSTR
                + (h0 + 3u * r) * 64u + seg * 8u;
  const f16* Bb = xk + (size_t)(4u + n) * 128u * XSTR + (h0 + 9u) * 64u + seg * 8u;
  unsigned ar0 = wv * 16u;
  unsigned br0 = wv * 32u;

  f32x4 acc[2][4] = {};

#pragma unroll
  for (unsigned t = 0; t < 2u; t++)
    gl16(Ab + (size_t)(ar0 + t * 8u + rsl) * XSTR, &gl[(ar0 + t * 8u) * 64u]);
#pragma unroll
  for (unsigned t = 0; t < 4u; t++)
    gl16(Bb + (size_t)(br0 + t * 8u + rsl) * XSTR, &gl[4096u + (br0 + t * 8u) * 64u]);

  for (unsigned s = 0; s < 8u; s++) {
    __syncthreads();
    if (s < 7u) {
      f16* base = &gl[((s + 1u) & 1u) * 12288u];
      unsigned off = (s + 1u) * 64u;
#pragma unroll
      for (unsigned t = 0; t < 2u; t++)
        gl16(Ab + off + (size_t)(ar0 + t * 8u + rsl) * XSTR, base + (ar0 + t * 8u) * 64u);
#pragma unroll
      for (unsigned t = 0; t < 4u; t++)
        gl16(Bb + off + (size_t)(br0 + t * 8u + rsl) * XSTR, base + 4096u + (br0 + t * 8u) * 64u);
    }
    const f16* bufA = &gl[(s & 1u) * 12288u];
    const f16* bufB = bufA + 4096u;
#pragma unroll
    for (unsigned t2 = 0; t2 < 2u; t2++) {
      unsigned L = t2 * 4u + quad;
      f16x8 a[2], bb[4];
#pragma unroll
      for (int ms = 0; ms < 2; ms++) {
        unsigned rr = wy * 32u + (unsigned)ms * 16u + l16;
        a[ms] = *(const f16x8*)&bufA[rr * 64u + (L ^ (rr & 7u)) * 8u];
      }
#pragma unroll
      for (int ns = 0; ns < 4; ns++) {
        unsigned rb = wx * 64u + (unsigned)ns * 16u + l16;
        bb[ns] = *(const f16x8*)&bufB[rb * 64u + (L ^ (rb & 7u)) * 8u];
      }
#pragma unroll
      for (int ms = 0; ms < 2; ms++)
#pragma unroll
        for (int ns = 0; ns < 4; ns++)
          acc[ms][ns] = __builtin_amdgcn_mfma_f32_16x16x32_f16(a[ms], bb[ns], acc[ms][ns], 0, 0, 0);
    }
  }

  f16* tp = t3p + ((size_t)(ks * 4u + n) * 11u + rki) * 16384u;
#pragma unroll
  for (int ms = 0; ms < 2; ms++) {
#pragma unroll
    for (int ns = 0; ns < 4; ns++) {
      unsigned c0 = cseg * 64u + wy * 32u + (unsigned)ms * 16u + quad * 4u;
      unsigned d  = wx * 64u + (unsigned)ns * 16u + l16;
#pragma unroll
      for (int reg = 0; reg < 4; reg++)
        tp[(size_t)(c0 + (unsigned)reg) * 128u + d] = (f16)acc[ms][ns][reg];
    }
  }
}

// ---------------------------------------------------------------- ep: t6T = p6 * t3 (mirror for rk>=11)
__global__ __launch_bounds__(256) void ep_kernel(const f16* __restrict__ t3p,
                                                 const float* __restrict__ p6,
                                                 f16* __restrict__ t6T) {
  unsigned idx = blockIdx.x * 256u + threadIdx.x;   // < 344064
  unsigned t   = idx >> 12;                          // n*21+rk
  unsigned rk  = t % 21u;
  unsigned n   = t / 21u;

  if (rk <= 10u) {
    unsigned d4 = idx & 31u;
    unsigned c  = (idx >> 5) & 127u;
    unsigned d0 = d4 * 4u;
    float s0 = 0.f, s1 = 0.f, s2 = 0.f, s3 = 0.f;
#pragma unroll
    for (unsigned ks = 0; ks < 8u; ks++) {
      f16x4 v = *(const f16x4*)(t3p + (((size_t)(ks * 4u + n) * 11u + rk) * 16384u + c * 128u + d0));
      s0 += (float)v[0]; s1 += (float)v[1]; s2 += (float)v[2]; s3 += (float)v[3];
    }
    const float* pp = p6 + ((size_t)c * 21u + rk) * 128u + d0;
    f16* ob = t6T + (size_t)(n * 128u + d0) * 2688u + rk * 128u + c;
    ob[0]        = (f16)(s0 * pp[0]);
    ob[2688]     = (f16)(s1 * pp[1]);
    ob[2 * 2688] = (f16)(s2 * pp[2]);
    ob[3 * 2688] = (f16)(s3 * pp[3]);
  } else {
    unsigned mrk = 20u - rk;          // t3[c,rk,d] = t3p_sum[mrk][d][c]
    unsigned c4 = idx & 31u;
    unsigned d  = (idx >> 5) & 127u;
    unsigned c0 = c4 * 4u;
    float s0 = 0.f, s1 = 0.f, s2 = 0.f, s3 = 0.f;
#pragma unroll
    for (unsigned ks = 0; ks < 8u; ks++) {
      f16x4 v = *(const f16x4*)(t3p + (((size_t)(ks * 4u + n) * 11u + mrk) * 16384u + d * 128u + c0));
      s0 += (float)v[0]; s1 += (float)v[1]; s2 += (float)v[2]; s3 += (float)v[3];
    }
    f16x4 o;
    o[0] = (f16)(s0 * p6[((size_t)(c0 + 0u) * 21u + rk) * 128u + d]);
    o[1] = (f16)(s1 * p6[((size_t)(c0 + 1u) * 21u + rk) * 128u + d]);
    o[2] = (f16)(s2 * p6[((size_t)(c0 + 2u) * 21u + rk) * 128u + d]);
    o[3] = (f16)(s3 * p6[((size_t)(c0 + 3u) * 21u + rk) * 128u + d]);
    *(f16x4*)(t6T + (size_t)(n * 128u + d) * 2688u + rk * 128u + c0) = o;
  }
}

// ---------------------------------------------------------------- outp (t8 split-K x4) — round-4 verbatim
// grid 1024 = n(4)*h(64)*g(4); block 256 (4 waves 2x2), tile 64w x 128d.
#define ALDS_STR 40
#define RT_STR   66
__global__ __launch_bounds__(256, 4) void outp_kernel(const f16* __restrict__ xk,
                                                      const float* __restrict__ p5,
                                                      const f16* __restrict__ t6T,
                                                      f16* __restrict__ t8p) {
  __shared__ float smem[8448];    // 33792 B; first 10240 B = 2 staging bufs, aliased as Rt later
  f16* Alds = (f16*)smem;

  unsigned b = blockIdx.x;
  unsigned g = b & 3u;
  unsigned h = (b >> 2) & 63u;
  unsigned n = b >> 8;

  unsigned tid  = threadIdx.x;
  unsigned wv   = tid >> 6;
  unsigned lane = tid & 63u;
  unsigned wy   = wv >> 1;
  unsigned wx   = wv & 1u;
  unsigned quad = lane >> 4;
  unsigned l16  = lane & 15u;
  unsigned wst  = tid & 63u;
  unsigned g8   = tid >> 6;

  unsigned cbase = g * 32u + g8 * 8u;
  const float* prow0 = p5 + (size_t)cbase * (21u * 4096u) + h * 64u + wst;
  const f16* bfb = t6T + (size_t)(n * 128u + wx * 64u + l16) * 2688u + g * 32u + quad * 8u;

  f32x4 acc[2][4] = {};
  f16 xv[8]; float pv[8];
  f16x8 bfc[4];

  { // prefetch chunk 0 (rk=0 -> r=0, kc=0)
    const f16* xrow = xk + (((size_t)n * 128u + cbase) * XROWS + h) * 64u + wst;
#pragma unroll
    for (int i = 0; i < 8; i++) { xv[i] = xrow[(size_t)i * XSTR]; pv[i] = prow0[(size_t)i * (21u * 4096u)]; }
#pragma unroll
    for (int ns = 0; ns < 4; ns++) bfc[ns] = *(const f16x8*)(bfb + (size_t)ns * 16u * 2688u);
  }

  for (unsigned j = 0; j < 21u; j++) {
    f16* Ag = Alds + (j & 1u) * 2560u;
    {
      f16x8 av;
#pragma unroll
      for (int i = 0; i < 8; i++) av[i] = (f16)((float)xv[i] * (1.0f + pv[i]));
      *(f16x8*)&Ag[wst * ALDS_STR + g8 * 8u] = av;
    }
    __syncthreads();

    f16x8 bfn[4];
    if (j < 20u) {   // register prefetch of chunk j+1 (overlaps MFMA below)
      unsigned rk = j + 1u;
      unsigned rr = rk / 3u;
      unsigned kcc = rk - rr * 3u;
      const f16* xrow = xk + (((size_t)(kcc * 4u + n) * 128u + cbase) * XROWS + (h + 3u * rr)) * 64u + wst;
      const float* prow = prow0 + rk * 4096u;
#pragma unroll
      for (int i = 0; i < 8; i++) { xv[i] = xrow[(size_t)i * XSTR]; pv[i] = prow[(size_t)i * (21u * 4096u)]; }
#pragma unroll
      for (int ns = 0; ns < 4; ns++) bfn[ns] = *(const f16x8*)(bfb + (size_t)ns * 16u * 2688u + rk * 128u);
    }

    f16x8 a[2];
#pragma unroll
    for (int ms = 0; ms < 2; ms++)
      a[ms] = *(const f16x8*)&Ag[(wy * 32u + (unsigned)ms * 16u + l16) * ALDS_STR + quad * 8u];
#pragma unroll
    for (int ms = 0; ms < 2; ms++)
#pragma unroll
      for (int ns = 0; ns < 4; ns++)
        acc[ms][ns] = __builtin_amdgcn_mfma_f32_16x16x32_f16(a[ms], bfc[ns], acc[ms][ns], 0, 0, 0);
#pragma unroll
    for (int ns = 0; ns < 4; ns++) bfc[ns] = bfn[ns];
  }

  // transpose via LDS for coalesced f16 partial stores: t8p[g][n][h][d][w]
  __syncthreads();
  float* Rt = smem;
#pragma unroll
  for (int ms = 0; ms < 2; ms++)
#pragma unroll
    for (int ns = 0; ns < 4; ns++) {
      unsigned w0 = wy * 32u + (unsigned)ms * 16u + quad * 4u;
      unsigned d  = wx * 64u + (unsigned)ns * 16u + l16;
#pragma unroll
      for (int reg = 0; reg < 4; reg++)
        Rt[d * RT_STR + w0 + (unsigned)reg] = acc[ms][ns][reg];
    }
  __syncthreads();
  f16* op = t8p + ((size_t)((g * 4u + n) * 64u + h)) * 8192u;
#pragma unroll
  for (unsigned it = 0; it < 4u; it++) {
    unsigned row = (tid >> 3) + it * 32u;
    unsigned w0  = (tid & 7u) * 8u;
    f16x8 o;
#pragma unroll
    for (int i = 0; i < 8; i++) o[i] = (f16)Rt[row * RT_STR + w0 + (unsigned)i];
    *(f16x8*)(op + row * 64u + w0) = o;
  }
}

// ---------------------------------------------------------------- red: out = FS * sum_g(t8p)
__global__ __launch_bounds__(256) void red_kernel(const f16* __restrict__ t8p,
                                                  float* __restrict__ out) {
  unsigned idx = blockIdx.x * 256u + threadIdx.x;
  unsigned w0 = (idx & 7u) * 8u;
  unsigned h  = (idx >> 3) & 63u;
  unsigned d  = (idx >> 9) & 127u;
  unsigned n  = idx >> 16;
  const float FS = 0.15430334996209192f;  // 8 / sqrt(2688)
  float s[8] = {};
#pragma unroll
  for (unsigned g = 0; g < 4u; g++) {
    f16x8 v = *(const f16x8*)(t8p + ((size_t)((g * 4u + n) * 64u + h)) * 8192u + d * 64u + w0);
#pragma unroll
    for (int i = 0; i < 8; i++) s[i] += (float)v[i];
  }
  f32x4 o0, o1;
#pragma unroll
  for (int i = 0; i < 4; i++) { o0[i] = s[i] * FS; o1[i] = s[i + 4] * FS; }
  float* op = out + ((size_t)(n * 128u + d) * 64u + h) * 64u + w0;
  *(f32x4*)op = o0;
  *(f32x4*)(op + 4) = o1;
}

// ---------------------------------------------------------------- launch
extern "C" void kernel_launch(void* const* d_in, const int* in_sizes, int n_in,
                              void* d_out, int out_size, void* d_ws, size_t ws_size,
                              hipStream_t stream) {
  const float* x  = (const float*)d_in[0];
  const float* p5 = (const float*)d_in[1];
  const float* p6 = (const float*)d_in[2];
  float* out = (float*)d_out;
  f16* xk  = (f16*)((char*)d_ws);
  f16* t6T = (f16*)((char*)d_ws + T6T_OFF);
  f16* t3p = (f16*)((char*)d_ws + T3P_OFF);
  f16* t8p = (f16*)((char*)d_ws + T8P_OFF);   // aliases t3p (dead after ep)

  unsigned prep_blocks = (3u * 4u * 128u * 82u * 32u + 255u) / 256u;  // 15744
  hipLaunchKernelGGL(prep_kernel, dim3(prep_blocks), dim3(256), 0, stream, x, xk);
  hipLaunchKernelGGL(gram_kernel, dim3(704),  dim3(256), 0, stream, xk, t3p);
  hipLaunchKernelGGL(ep_kernel,   dim3(1344), dim3(256), 0, stream, t3p, p6, t6T);
  hipLaunchKernelGGL(outp_kernel, dim3(1024), dim3(256), 0, stream, xk, p5, t6T, t8p);
  hipLaunchKernelGGL(red_kernel,  dim3(1024), dim3(256), 0, stream, t8p, out);
}